// Round 1
// baseline (299.230 us; speedup 1.0000x reference)
//
#include <hip/hip_runtime.h>
#include <math.h>

#define EPSV 1e-5f

typedef __attribute__((ext_vector_type(8))) short short8;
typedef __attribute__((ext_vector_type(4))) float f32x4;

// pack two f32 -> two bf16 (RTNE) in one uint
static __device__ __forceinline__ unsigned bfpack2(float lo, float hi) {
    union { float f; unsigned u; } a, b;
    a.f = lo; b.f = hi;
    unsigned ua = a.u + 0x7fffu + ((a.u >> 16) & 1u);
    unsigned ub = b.u + 0x7fffu + ((b.u >> 16) & 1u);
    return (ua >> 16) | (ub & 0xffff0000u);
}

// ---------------------------------------------------------------------------
// K1 gram: G[b] = X_b^T X_b via bf16 MFMA (16x16x32), plus column sums
// (for the bias outer-product terms). Flat grid 2048:
//   id 0..1023:    x-path (P=1024), b = id&63 (b -> XCD affinity), tile = id>>6
//   id 1024..2047: z-path (P=256)
// tile = (ci<<2)|cj : output 64x64 tile [ci cols] x [cj cols].
// Staging: per 64-p chunk, thread owns column cl=t&63, p-phase ph=t>>6;
// 16 scalar loads (lanes contiguous in c -> coalesced 256B), packed to bf16
// transposed LDS [64 c][72 pad].
// ---------------------------------------------------------------------------
__global__ __launch_bounds__(256) void gram(
    const float* __restrict__ Xx, const float* __restrict__ Xz,
    float* __restrict__ Gx, float* __restrict__ Gz,
    float* __restrict__ csx, float* __restrict__ csz)
{
    __shared__ __align__(16) unsigned short AT[64 * 72];
    __shared__ __align__(16) unsigned short BT[64 * 72];
    __shared__ float csr[256];
    int id = blockIdx.x;
    const float* X; float* G; float* cs; int P;
    if (id < 1024) { X = Xx; G = Gx; cs = csx; P = 1024; }
    else { id -= 1024; X = Xz; G = Gz; cs = csz; P = 256; }
    const int b = id & 63;
    const int tile = id >> 6;
    const int ci = tile >> 2, cj = tile & 3;
    const int nk = P >> 6;
    const int t = threadIdx.x;
    const int cl = t & 63, ph = t >> 6;
    const int w = t >> 6, quad = (t >> 4) & 3, lane16 = t & 15;
    const float* Xb = X + (long)b * P * 256;
    const float* Acol = Xb + ci * 64 + cl;
    const float* Bcol = Xb + cj * 64 + cl;
    const bool diag = (ci == cj);

    f32x4 acc[4] = {{0.f,0.f,0.f,0.f},{0.f,0.f,0.f,0.f},{0.f,0.f,0.f,0.f},{0.f,0.f,0.f,0.f}};
    float csum = 0.f;

    for (int kc = 0; kc < nk; ++kc) {
        const int p0 = kc * 64 + ph * 16;
        float va[16], vb[16];
#pragma unroll
        for (int k = 0; k < 16; ++k) va[k] = Acol[(long)(p0 + k) * 256];
        if (!diag) {
#pragma unroll
            for (int k = 0; k < 16; ++k) vb[k] = Bcol[(long)(p0 + k) * 256];
        } else {
#pragma unroll
            for (int k = 0; k < 16; ++k) { vb[k] = va[k]; csum += va[k]; }
        }
        uint4 a0, a1, b0, b1;
        a0.x = bfpack2(va[0], va[1]);   a0.y = bfpack2(va[2], va[3]);
        a0.z = bfpack2(va[4], va[5]);   a0.w = bfpack2(va[6], va[7]);
        a1.x = bfpack2(va[8], va[9]);   a1.y = bfpack2(va[10], va[11]);
        a1.z = bfpack2(va[12], va[13]); a1.w = bfpack2(va[14], va[15]);
        b0.x = bfpack2(vb[0], vb[1]);   b0.y = bfpack2(vb[2], vb[3]);
        b0.z = bfpack2(vb[4], vb[5]);   b0.w = bfpack2(vb[6], vb[7]);
        b1.x = bfpack2(vb[8], vb[9]);   b1.y = bfpack2(vb[10], vb[11]);
        b1.z = bfpack2(vb[12], vb[13]); b1.w = bfpack2(vb[14], vb[15]);
        __syncthreads();   // previous chunk's MFMA reads done
        *(uint4*)&AT[cl * 72 + ph * 16]     = a0;
        *(uint4*)&AT[cl * 72 + ph * 16 + 8] = a1;
        *(uint4*)&BT[cl * 72 + ph * 16]     = b0;
        *(uint4*)&BT[cl * 72 + ph * 16 + 8] = b1;
        __syncthreads();
#pragma unroll
        for (int ks = 0; ks < 2; ++ks) {
            const int ko = ks * 32 + quad * 8;
            short8 bfrag = *(const short8*)&BT[(w * 16 + lane16) * 72 + ko];
#pragma unroll
            for (int mi = 0; mi < 4; ++mi) {
                short8 afrag = *(const short8*)&AT[(mi * 16 + lane16) * 72 + ko];
                acc[mi] = __builtin_amdgcn_mfma_f32_16x16x32_bf16(afrag, bfrag, acc[mi], 0, 0, 0);
            }
        }
    }
    // C/D: col = lane16 (within w-tile), row = quad*4 + r (within mi-tile)
#pragma unroll
    for (int mi = 0; mi < 4; ++mi) {
        long row = (long)(b * 256 + ci * 64 + mi * 16 + quad * 4);
        int col = cj * 64 + w * 16 + lane16;
#pragma unroll
        for (int r = 0; r < 4; ++r)
            G[(row + r) * 256 + col] = acc[mi][r];
    }
    if (diag) {
        csr[ph * 64 + cl] = csum;
        __syncthreads();
        if (t < 64)
            cs[b * 256 + ci * 64 + t] = csr[t] + csr[64 + t] + csr[128 + t] + csr[192 + t];
    }
}

// ---------------------------------------------------------------------------
// K2 proj: kxr[b] = Wx^T Gx_b + bx (x) csx_b ; kern[b] = Wz^T Gz_b + bz (x) csz_b.
// G is symmetric => MFMA B-operand reads G rows directly (k = c' contiguous).
// A = W^T staged bf16 once per block ([64 n][264 pad], k = c').
// Flat grid 512: b = id&63, s = id>>6 (s<4: x-path ct=s; else z-path ct=s&3).
// ---------------------------------------------------------------------------
__global__ __launch_bounds__(256) void proj(
    const float* __restrict__ Gx, const float* __restrict__ csx,
    const float* __restrict__ Wx, const float* __restrict__ bx,
    float* __restrict__ kxr,
    const float* __restrict__ Gz, const float* __restrict__ csz,
    const float* __restrict__ Wz, const float* __restrict__ bz,
    float* __restrict__ kern)
{
    __shared__ __align__(16) unsigned short ATW[64 * 264];
    __shared__ __align__(16) unsigned short BTC[64 * 72];
    const int t = threadIdx.x;
    const int id = blockIdx.x;
    const int b = id & 63, s = id >> 6;
    const float *G, *cs, *W, *bias; float* O;
    if (s < 4) { G = Gx; cs = csx; W = Wx; bias = bx; O = kxr; }
    else       { G = Gz; cs = csz; W = Wz; bias = bz; O = kern; }
    const int ct = s & 3;
    const int n = t & 63, ph = t >> 6;
    // stage W^T -> bf16: ATW[n][c'], c' = ph*64 + cc*16 + k
#pragma unroll
    for (int cc = 0; cc < 4; ++cc) {
        float v[16];
#pragma unroll
        for (int k = 0; k < 16; ++k) v[k] = W[(ph * 64 + cc * 16 + k) * 64 + n];
        uint4 p0, p1;
        p0.x = bfpack2(v[0], v[1]);   p0.y = bfpack2(v[2], v[3]);
        p0.z = bfpack2(v[4], v[5]);   p0.w = bfpack2(v[6], v[7]);
        p1.x = bfpack2(v[8], v[9]);   p1.y = bfpack2(v[10], v[11]);
        p1.z = bfpack2(v[12], v[13]); p1.w = bfpack2(v[14], v[15]);
        *(uint4*)&ATW[n * 264 + ph * 64 + cc * 16]     = p0;
        *(uint4*)&ATW[n * 264 + ph * 64 + cc * 16 + 8] = p1;
    }
    const int row = t >> 2, cq = t & 3;
    const int w = t >> 6, quad = (t >> 4) & 3, lane16 = t & 15;
    const float* Grow = G + ((long)(b * 256 + ct * 64 + row)) * 256 + cq * 16;
    f32x4 acc[4] = {{0.f,0.f,0.f,0.f},{0.f,0.f,0.f,0.f},{0.f,0.f,0.f,0.f},{0.f,0.f,0.f,0.f}};
    for (int kc = 0; kc < 4; ++kc) {
        float4 g0 = *(const float4*)(Grow + kc * 64 + 0);
        float4 g1 = *(const float4*)(Grow + kc * 64 + 4);
        float4 g2 = *(const float4*)(Grow + kc * 64 + 8);
        float4 g3 = *(const float4*)(Grow + kc * 64 + 12);
        uint4 pk0, pk1;
        pk0.x = bfpack2(g0.x, g0.y); pk0.y = bfpack2(g0.z, g0.w);
        pk0.z = bfpack2(g1.x, g1.y); pk0.w = bfpack2(g1.z, g1.w);
        pk1.x = bfpack2(g2.x, g2.y); pk1.y = bfpack2(g2.z, g2.w);
        pk1.z = bfpack2(g3.x, g3.y); pk1.w = bfpack2(g3.z, g3.w);
        __syncthreads();
        *(uint4*)&BTC[row * 72 + cq * 16]     = pk0;
        *(uint4*)&BTC[row * 72 + cq * 16 + 8] = pk1;
        __syncthreads();
#pragma unroll
        for (int ks = 0; ks < 2; ++ks) {
            const int ko = ks * 32 + quad * 8;
            short8 bfrag = *(const short8*)&BTC[(w * 16 + lane16) * 72 + ko];
#pragma unroll
            for (int mi = 0; mi < 4; ++mi) {
                short8 afrag = *(const short8*)&ATW[(mi * 16 + lane16) * 264 + kc * 64 + ko];
                acc[mi] = __builtin_amdgcn_mfma_f32_16x16x32_bf16(afrag, bfrag, acc[mi], 0, 0, 0);
            }
        }
    }
    const int col = ct * 64 + w * 16 + lane16;
    const float csv = cs[b * 256 + col];
#pragma unroll
    for (int mi = 0; mi < 4; ++mi) {
        const int nrow = mi * 16 + quad * 4;
#pragma unroll
        for (int r = 0; r < 4; ++r)
            O[((long)(b * 64 + nrow + r)) * 256 + col] = acc[mi][r] + bias[nrow + r] * csv;
    }
}

// ---------------------------------------------------------------------------
// K3: dy = kern @ Wdyn + bdyn. dyb[b][n][68]: 0..63 point, 64..66 depth.
// (unchanged from previous verified kernel)
// ---------------------------------------------------------------------------
__global__ __launch_bounds__(256) void dy_all(
    const float* __restrict__ kern, const float* __restrict__ Wdyn,
    const float* __restrict__ bdyn, float* __restrict__ dyb)
{
    __shared__ float Ac[16 * 64];
    __shared__ float Wc[16 * 64];
    __shared__ float Wd3[48];
    const int b = blockIdx.x, t = threadIdx.x;
    const int tr = t >> 4, tc = t & 15;
    float acc[4][4];
#pragma unroll
    for (int j = 0; j < 4; ++j) {
        float bj = bdyn[3 + tc * 4 + j];
        acc[0][j] = bj; acc[1][j] = bj; acc[2][j] = bj; acc[3][j] = bj;
    }
    const int lr = t >> 2, lc = (t & 3) * 4;
    const int wl = t >> 4, wj = (t & 15) * 4;
    const int nwd = t / 3, jwd = t - nwd * 3;
    float wdacc = 0.f;
    float4 av = *(const float4*)(kern + ((long)(b * 64 + lr)) * 256 + lc);
    float w0 = Wdyn[wl * 67 + 3 + wj + 0];
    float w1 = Wdyn[wl * 67 + 3 + wj + 1];
    float w2 = Wdyn[wl * 67 + 3 + wj + 2];
    float w3 = Wdyn[wl * 67 + 3 + wj + 3];
    float wdr = (t < 48) ? Wdyn[(t / 3) * 67 + (t % 3)] : 0.f;

    for (int c0 = 0; c0 < 256; c0 += 16) {
        Ac[(lc+0)*64 + lr] = av.x; Ac[(lc+1)*64 + lr] = av.y;
        Ac[(lc+2)*64 + lr] = av.z; Ac[(lc+3)*64 + lr] = av.w;
        Wc[wl*64 + wj+0] = w0; Wc[wl*64 + wj+1] = w1;
        Wc[wl*64 + wj+2] = w2; Wc[wl*64 + wj+3] = w3;
        if (t < 48) Wd3[t] = wdr;
        __syncthreads();
        if (c0 + 16 < 256) {
            av = *(const float4*)(kern + ((long)(b * 64 + lr)) * 256 + c0 + 16 + lc);
            w0 = Wdyn[(c0 + 16 + wl) * 67 + 3 + wj + 0];
            w1 = Wdyn[(c0 + 16 + wl) * 67 + 3 + wj + 1];
            w2 = Wdyn[(c0 + 16 + wl) * 67 + 3 + wj + 2];
            w3 = Wdyn[(c0 + 16 + wl) * 67 + 3 + wj + 3];
            if (t < 48) wdr = Wdyn[(c0 + 16 + t / 3) * 67 + (t % 3)];
        }
#pragma unroll
        for (int cl = 0; cl < 16; ++cl) {
            float4 a = *(float4*)&Ac[cl * 64 + tr * 4];
            float4 w = *(float4*)&Wc[cl * 64 + tc * 4];
            acc[0][0]+=a.x*w.x; acc[0][1]+=a.x*w.y; acc[0][2]+=a.x*w.z; acc[0][3]+=a.x*w.w;
            acc[1][0]+=a.y*w.x; acc[1][1]+=a.y*w.y; acc[1][2]+=a.y*w.z; acc[1][3]+=a.y*w.w;
            acc[2][0]+=a.z*w.x; acc[2][1]+=a.z*w.y; acc[2][2]+=a.z*w.z; acc[2][3]+=a.z*w.w;
            acc[3][0]+=a.w*w.x; acc[3][1]+=a.w*w.y; acc[3][2]+=a.w*w.z; acc[3][3]+=a.w*w.w;
        }
        if (t < 192) {
#pragma unroll
            for (int cl = 0; cl < 16; ++cl)
                wdacc += Ac[cl * 64 + nwd] * Wd3[cl * 3 + jwd];
        }
        __syncthreads();
    }
#pragma unroll
    for (int i = 0; i < 4; ++i) {
        float4 o = make_float4(acc[i][0], acc[i][1], acc[i][2], acc[i][3]);
        *(float4*)(dyb + ((long)(b * 64 + tr * 4 + i)) * 68 + tc * 4) = o;
    }
    if (t < 192) dyb[((long)(b * 64 + nwd)) * 68 + 64 + jwd] = wdacc + bdyn[jwd];
}

// ---------------------------------------------------------------------------
// K4: depth conv + point GEMM per (batch, 64-channel tile). grid (4, 64).
// (unchanged from previous verified kernel)
// ---------------------------------------------------------------------------
__global__ __launch_bounds__(256) void depthpoint(
    const float* __restrict__ dyb, const float* __restrict__ v,
    const float* __restrict__ g, const float* __restrict__ Wp,
    float* __restrict__ point, float* __restrict__ partials)
{
    __shared__ float smem[13312];
    float* wpT = smem;           // [m][n] stride 68
    float* wd3 = smem + 4352;    // [m][4]
    float* vt  = smem + 4608;    // [m][lc] stride 68
    float* dep = smem + 8960;    // [m][c_loc] stride 68
    float* rs  = vt;             // alias after depth phase

    const int t = threadIdx.x;
    const int b = blockIdx.y, ct = blockIdx.x, c0 = ct * 64;
    const int tr = t >> 4, tc = t & 15;

#pragma unroll
    for (int i = 0; i < 4; ++i) {
        int idx = t + i * 256; int n = idx >> 4, m0 = (idx & 15) * 4;
        float4 w4 = *(const float4*)(dyb + ((long)(b * 64 + n)) * 68 + m0);
        wpT[(m0+0)*68 + n] = w4.x; wpT[(m0+1)*68 + n] = w4.y;
        wpT[(m0+2)*68 + n] = w4.z; wpT[(m0+3)*68 + n] = w4.w;
    }
    if (t < 64) {
        long o = ((long)(b * 64 + t)) * 68 + 64;
        wd3[t*4+0] = dyb[o+0]; wd3[t*4+1] = dyb[o+1]; wd3[t*4+2] = dyb[o+2];
    }
    {
        int m = t >> 2, lc0 = (t & 3) * 17;
#pragma unroll
        for (int k = 0; k < 17; ++k) {
            int lc = lc0 + k;
            if (lc < 66) {
                int c = c0 - 1 + lc;
                vt[m * 68 + lc] = (c >= 0 && c < 256) ? v[((long)(b * 64 + m)) * 256 + c] : 0.f;
            }
        }
    }
    __syncthreads();
#pragma unroll
    for (int im = 0; im < 4; ++im) {
        int m = tr * 4 + im;
        float w0 = wd3[m*4+0], w1 = wd3[m*4+1], w2 = wd3[m*4+2];
#pragma unroll
        for (int jc = 0; jc < 4; ++jc) {
            int cl = tc * 4 + jc;
            float d = w0 * vt[m*68 + cl] + w1 * vt[m*68 + cl + 1] + w2 * vt[m*68 + cl + 2];
            dep[m*68 + cl] = fmaxf(d, 0.f);
        }
    }
    __syncthreads();
    float acc[4][4] = {};
#pragma unroll 16
    for (int m = 0; m < 64; ++m) {
        float4 a4 = *(float4*)&wpT[m * 68 + tr * 4];
        float4 d4 = *(float4*)&dep[m * 68 + tc * 4];
        acc[0][0]+=a4.x*d4.x; acc[0][1]+=a4.x*d4.y; acc[0][2]+=a4.x*d4.z; acc[0][3]+=a4.x*d4.w;
        acc[1][0]+=a4.y*d4.x; acc[1][1]+=a4.y*d4.y; acc[1][2]+=a4.y*d4.z; acc[1][3]+=a4.y*d4.w;
        acc[2][0]+=a4.z*d4.x; acc[2][1]+=a4.z*d4.y; acc[2][2]+=a4.z*d4.z; acc[2][3]+=a4.z*d4.w;
        acc[3][0]+=a4.w*d4.x; acc[3][1]+=a4.w*d4.y; acc[3][2]+=a4.w*d4.z; acc[3][3]+=a4.w*d4.w;
    }
    int cg = c0 + tc * 4;
    float4 g4  = *(const float4*)(g + cg);
    float4 wp4 = *(const float4*)(Wp + cg);
    float gw0 = g4.x*wp4.x, gw1 = g4.y*wp4.y, gw2 = g4.z*wp4.z, gw3 = g4.w*wp4.w;
#pragma unroll
    for (int i = 0; i < 4; ++i) {
        float4 o = make_float4(acc[i][0], acc[i][1], acc[i][2], acc[i][3]);
        *(float4*)(point + ((long)(b * 64 + tr * 4 + i)) * 256 + cg) = o;
        float s  = o.x + o.y + o.z + o.w;
        float s2 = o.x*o.x + o.y*o.y + o.z*o.z + o.w*o.w;
        float dg = o.x*gw0 + o.y*gw1 + o.z*gw2 + o.w*gw3;
        rs[0*1088 + (tr*4+i)*17 + tc] = s;
        rs[1*1088 + (tr*4+i)*17 + tc] = s2;
        rs[2*1088 + (tr*4+i)*17 + tc] = dg;
    }
    __syncthreads();
    if (t < 64) {
        float s = 0.f, s2 = 0.f, dg = 0.f;
#pragma unroll
        for (int j = 0; j < 16; ++j) {
            s  += rs[t*17 + j];
            s2 += rs[1088 + t*17 + j];
            dg += rs[2176 + t*17 + j];
        }
        long base = ((long)(b * 4 + ct)) * 192;
        partials[base + t]        = s;
        partials[base + 64 + t]   = s2;
        partials[base + 128 + t]  = dg;
    }
}

// ---------------------------------------------------------------------------
// K5: LN stats + proto (closed form) + tem. Emits murr[b][n]=(rr,-mu*rr),
// AB[b] = (g_norm*tem, b_norm*tem). (unchanged from previous verified kernel)
// ---------------------------------------------------------------------------
__global__ __launch_bounds__(256) void lntem(
    const float* __restrict__ partials, const float* __restrict__ point,
    const float* __restrict__ g, const float* __restrict__ bta,
    const float* __restrict__ Wp, const float* __restrict__ bp,
    float* __restrict__ murr, float* __restrict__ AB)
{
    __shared__ float sA[256], sB[256];
    __shared__ float wnv[64];
    __shared__ float tot[4];
    const int b = blockIdx.x, t = threadIdx.x;
    const int c = t;
    float gc = g[c], bc = bta[c], wpc = Wp[c];
    sA[t] = gc * wpc; sB[t] = bc * wpc;
    __syncthreads();
    for (int off = 128; off >= 1; off >>= 1) {
        if (t < off) { sA[t] += sA[t+off]; sB[t] += sB[t+off]; }
        __syncthreads();
    }
    if (t == 0) { tot[0] = sA[0]; tot[1] = sB[0] + bp[0]; }
    __syncthreads();
    float Sgw = tot[0], Sbw = tot[1];

    float protoe = 0.f, mu = 0.f, rr = 0.f;
    if (t < 64) {
        float S1 = 0.f, S2 = 0.f, Sdg = 0.f;
#pragma unroll
        for (int ct = 0; ct < 4; ++ct) {
            long o = ((long)(b * 4 + ct)) * 192;
            S1 += partials[o + t]; S2 += partials[o + 64 + t]; Sdg += partials[o + 128 + t];
        }
        mu = S1 * (1.f / 256.f);
        float var = S2 * (1.f / 256.f) - mu * mu;
        rr = rsqrtf(var + EPSV);
        protoe = rr * (Sdg - mu * Sgw) + Sbw;
        wnv[t] = protoe * rr;
        murr[b * 128 + 2*t]     = rr;
        murr[b * 128 + 2*t + 1] = -mu * rr;
    }
    __syncthreads();
    sA[t] = (t < 64) ? protoe * rr * mu : 0.f;
    sB[t] = (t < 64) ? protoe : 0.f;
    __syncthreads();
    for (int off = 128; off >= 1; off >>= 1) {
        if (t < off) { sA[t] += sA[t+off]; sB[t] += sB[t+off]; }
        __syncthreads();
    }
    if (t == 0) { tot[2] = sA[0]; tot[3] = sB[0]; }
    __syncthreads();
    float Bv = tot[2], Sv = tot[3];

    const float* pcol = point + (long)b * 64 * 256 + c;
    float a0 = 0.f, a1 = 0.f, a2 = 0.f, a3 = 0.f;
#pragma unroll
    for (int n = 0; n < 64; n += 4) {
        a0 += wnv[n+0] * pcol[(n+0) * 256];
        a1 += wnv[n+1] * pcol[(n+1) * 256];
        a2 += wnv[n+2] * pcol[(n+2) * 256];
        a3 += wnv[n+3] * pcol[(n+3) * 256];
    }
    float accA = a0 + a1 + a2 + a3;
    float x = gc * (accA - Bv) + bc * Sv;
    float temv = 1.f / (1.f + expf(-x));
    AB[b * 512 + c]       = gc * temv;
    AB[b * 512 + 256 + c] = bc * temv;
}

// ---------------------------------------------------------------------------
// K6 buildM: kxs[n][c] = (point*rr - mu*rr)*g*tem + b*tem (same formula the
// old final kernel used). MT[b][cout][cin] = sum_n kxs[n][cout] * Wx[cin][n]
// (bf16, cin contiguous -> final2 MFMA B-operand). svec[b][c] = sum_n bx[n]*kxs[n][c].
// Flat grid 256: b = id&63, mt = id>>6 (cout 64-tile). fp32 VALU.
// ---------------------------------------------------------------------------
__global__ __launch_bounds__(256) void buildM(
    const float* __restrict__ point, const float* __restrict__ murr,
    const float* __restrict__ AB, const float* __restrict__ Wx,
    const float* __restrict__ bx,
    unsigned short* __restrict__ MT, float* __restrict__ svec)
{
    __shared__ float ks_s[64 * 68];   // kxs [n][cout-local]
    __shared__ float wt_s[64 * 68];   // WxT chunk [n][cin-local]
    const int t = threadIdx.x;
    const int id = blockIdx.x;
    const int b = id & 63, mt = id >> 6;
    {
        const int n = t >> 2, q = t & 3;
        const float rn = murr[b * 128 + 2 * n], qn = murr[b * 128 + 2 * n + 1];
        const float* prow = point + ((long)(b * 64 + n)) * 256 + mt * 64 + q * 16;
        const float* Arow = AB + b * 512 + mt * 64 + q * 16;
#pragma unroll
        for (int j = 0; j < 4; ++j) {
            float4 p4 = *(const float4*)(prow + j * 4);
            float4 A4 = *(const float4*)(Arow + j * 4);
            float4 B4 = *(const float4*)(Arow + 256 + j * 4);
            float4 kv;
            kv.x = (p4.x * rn + qn) * A4.x + B4.x;
            kv.y = (p4.y * rn + qn) * A4.y + B4.y;
            kv.z = (p4.z * rn + qn) * A4.z + B4.z;
            kv.w = (p4.w * rn + qn) * A4.w + B4.w;
            *(float4*)&ks_s[n * 68 + q * 16 + j * 4] = kv;
        }
    }
    __syncthreads();
    if (t < 64) {
        float sv = 0.f;
#pragma unroll
        for (int n2 = 0; n2 < 64; ++n2) sv += bx[n2] * ks_s[n2 * 68 + t];
        svec[b * 256 + mt * 64 + t] = sv;
    }
    const int tr = t >> 4, tc = t & 15;
    const int nw = t & 63, ph = t >> 6;
    for (int cc = 0; cc < 4; ++cc) {
        float wv[16];
#pragma unroll
        for (int k = 0; k < 16; ++k) wv[k] = Wx[(cc * 64 + ph * 16 + k) * 64 + nw];
        __syncthreads();   // previous chunk's compute reads done
#pragma unroll
        for (int k = 0; k < 16; ++k) wt_s[nw * 68 + ph * 16 + k] = wv[k];
        __syncthreads();
        float a2[4][4] = {};
#pragma unroll 16
        for (int n2 = 0; n2 < 64; ++n2) {
            float4 a4 = *(float4*)&ks_s[n2 * 68 + tr * 4];   // cout
            float4 w4 = *(float4*)&wt_s[n2 * 68 + tc * 4];   // cin
            a2[0][0]+=a4.x*w4.x; a2[0][1]+=a4.x*w4.y; a2[0][2]+=a4.x*w4.z; a2[0][3]+=a4.x*w4.w;
            a2[1][0]+=a4.y*w4.x; a2[1][1]+=a4.y*w4.y; a2[1][2]+=a4.y*w4.z; a2[1][3]+=a4.y*w4.w;
            a2[2][0]+=a4.z*w4.x; a2[2][1]+=a4.z*w4.y; a2[2][2]+=a4.z*w4.z; a2[2][3]+=a4.z*w4.w;
            a2[3][0]+=a4.w*w4.x; a2[3][1]+=a4.w*w4.y; a2[3][2]+=a4.w*w4.z; a2[3][3]+=a4.w*w4.w;
        }
#pragma unroll
        for (int i = 0; i < 4; ++i) {
            uint2 pk;
            pk.x = bfpack2(a2[i][0], a2[i][1]);
            pk.y = bfpack2(a2[i][2], a2[i][3]);
            *(uint2*)&MT[((long)(b * 256 + mt * 64 + tr * 4 + i)) * 256 + cc * 64 + tc * 4] = pk;
        }
    }
}

// ---------------------------------------------------------------------------
// K7 final2: x_corr = X_b @ M + svec via bf16 MFMA (A = x rows, k=cin
// contiguous -> no transpose; B = MT rows, global short8 frag loads, L2-hot),
// then row LN + relu + residual, fully vectorized epilogue via LDS roundtrip.
// Flat grid 1024: b = id&63 (XCD affinity for MT_b), pt = id>>6 (64-row tile).
// ---------------------------------------------------------------------------
__global__ __launch_bounds__(256) void final2(
    const float* __restrict__ xf, const unsigned short* __restrict__ MT,
    const float* __restrict__ svec, const float* __restrict__ g,
    const float* __restrict__ bt, float* __restrict__ out)
{
    __shared__ __align__(16) float SlArr[64 * 132];   // 33792B: XT (bf16) / Sl (f32) union
    __shared__ float red1[256], red2[256];
    __shared__ float muS[64], rrS[64];
    unsigned short* XT = (unsigned short*)SlArr;      // [64 p][264 pad] bf16
    float* Sl = SlArr;                                // [64 p][132] f32
    const int t = threadIdx.x;
    const int id = blockIdx.x;
    const int b = id & 63, pt = id >> 6;
    const int w = t >> 6, quad = (t >> 4) & 3, lane16 = t & 15;
    const float* Xb = xf + ((long)(b * 1024 + pt * 64)) * 256;
    {
        const int p = t >> 2, q = t & 3;
#pragma unroll
        for (int j = 0; j < 4; ++j)
#pragma unroll
            for (int i = 0; i < 4; ++i) {
                const int c = j * 64 + q * 16 + i * 4;
                float4 v = *(const float4*)(Xb + (long)p * 256 + c);
                uint2 pk;
                pk.x = bfpack2(v.x, v.y);
                pk.y = bfpack2(v.z, v.w);
                *(uint2*)&XT[p * 264 + c] = pk;
            }
    }
    __syncthreads();
    f32x4 acc[4][4] = {};   // [mi (rows)][ni (cols)]
    const unsigned short* Mb = MT + (long)b * 65536;
    for (int ks = 0; ks < 8; ++ks) {
        const int ko = ks * 32 + quad * 8;
        short8 bf4[4], af4[4];
#pragma unroll
        for (int ni = 0; ni < 4; ++ni)
            bf4[ni] = *(const short8*)(Mb + (long)(w * 64 + ni * 16 + lane16) * 256 + ko);
#pragma unroll
        for (int mi = 0; mi < 4; ++mi)
            af4[mi] = *(const short8*)&XT[(mi * 16 + lane16) * 264 + ko];
#pragma unroll
        for (int mi = 0; mi < 4; ++mi)
#pragma unroll
            for (int ni = 0; ni < 4; ++ni)
                acc[mi][ni] = __builtin_amdgcn_mfma_f32_16x16x32_bf16(af4[mi], bf4[ni], acc[mi][ni], 0, 0, 0);
    }
    // add svec, per-row (256-col) sums for LN
    float sv4[4];
#pragma unroll
    for (int ni = 0; ni < 4; ++ni) sv4[ni] = svec[b * 256 + w * 64 + ni * 16 + lane16];
#pragma unroll
    for (int mi = 0; mi < 4; ++mi)
#pragma unroll
        for (int r = 0; r < 4; ++r) {
            float s1 = 0.f, s2 = 0.f;
#pragma unroll
            for (int ni = 0; ni < 4; ++ni) {
                float v = acc[mi][ni][r] + sv4[ni];
                acc[mi][ni][r] = v;
                s1 += v; s2 += v * v;
            }
            // butterfly over the 16 lanes of this quad (row lives on lane16 0..15)
#pragma unroll
            for (int m = 1; m <= 8; m <<= 1) {
                s1 += __shfl_xor(s1, m);
                s2 += __shfl_xor(s2, m);
            }
            if (lane16 == 0) {
                red1[(mi * 16 + quad * 4 + r) * 4 + w] = s1;
                red2[(mi * 16 + quad * 4 + r) * 4 + w] = s2;
            }
        }
    __syncthreads();
    if (t < 64) {
        float sa = red1[t*4] + red1[t*4+1] + red1[t*4+2] + red1[t*4+3];
        float sb = red2[t*4] + red2[t*4+1] + red2[t*4+2] + red2[t*4+3];
        float m = sa * (1.f / 256.f);
        muS[t] = m;
        rrS[t] = rsqrtf(sb * (1.f / 256.f) - m * m + EPSV);
    }
    // scatter (MFMA layout) -> LDS -> vectorized LN+relu+residual store, 2 halves
#pragma unroll
    for (int h = 0; h < 2; ++h) {
        __syncthreads();
        if ((w >> 1) == h) {
            const int chalf = (w & 1) * 64;
#pragma unroll
            for (int mi = 0; mi < 4; ++mi)
#pragma unroll
                for (int ni = 0; ni < 4; ++ni)
#pragma unroll
                    for (int r = 0; r < 4; ++r)
                        Sl[(mi * 16 + quad * 4 + r) * 132 + chalf + ni * 16 + lane16] = acc[mi][ni][r];
        }
        __syncthreads();
        {
            const int p = t >> 2, q = t & 3;
            const float m = muS[p], rr = rrS[p];
            const long grow = ((long)(b * 1024 + pt * 64 + p)) * 256;
#pragma unroll
            for (int j = 0; j < 8; ++j) {
                const int cl = q * 32 + j * 4;
                const int c = h * 128 + cl;
                float4 a  = *(float4*)&Sl[p * 132 + cl];
                float4 g4 = *(const float4*)(g + c);
                float4 b4 = *(const float4*)(bt + c);
                float4 xv = *(const float4*)(xf + grow + c);
                float4 o;
                o.x = xv.x + fmaxf((a.x - m) * rr * g4.x + b4.x, 0.f);
                o.y = xv.y + fmaxf((a.y - m) * rr * g4.y + b4.y, 0.f);
                o.z = xv.z + fmaxf((a.z - m) * rr * g4.z + b4.z, 0.f);
                o.w = xv.w + fmaxf((a.w - m) * rr * g4.w + b4.w, 0.f);
                *(float4*)(out + grow + c) = o;
            }
        }
    }
}

extern "C" void kernel_launch(void* const* d_in, const int* in_sizes, int n_in,
                              void* d_out, int out_size, void* d_ws, size_t ws_size,
                              hipStream_t stream)
{
    (void)in_sizes; (void)n_in; (void)out_size; (void)ws_size;
    const float* x_feat = (const float*)d_in[0];
    const float* z_feat = (const float*)d_in[1];
    const float* Wz     = (const float*)d_in[2];
    const float* bz     = (const float*)d_in[3];
    const float* Wx     = (const float*)d_in[4];
    const float* bx     = (const float*)d_in[5];
    const float* Wdyn   = (const float*)d_in[6];
    const float* bdyn   = (const float*)d_in[7];
    const float* g_norm = (const float*)d_in[8];
    const float* b_norm = (const float*)d_in[9];
    const float* Wp     = (const float*)d_in[10];
    const float* bp     = (const float*)d_in[11];
    const float* g_ln   = (const float*)d_in[12];
    const float* b_ln   = (const float*)d_in[13];
    float* out = (float*)d_out;

    float* ws       = (float*)d_ws;
    float* Gx       = ws;                    // 4,194,304 f32
    float* Gz       = Gx + 4194304;          // 4,194,304
    float* kern     = Gz + 4194304;          // 1,048,576
    float* kxr      = kern + 1048576;        // 1,048,576
    float* point    = kxr + 1048576;         // 1,048,576
    float* dyb      = point + 1048576;       //   278,528
    float* partials = dyb + 278528;          //    49,152
    float* murr     = partials + 49152;      //     8,192
    float* AB       = murr + 8192;           //    32,768
    float* csx      = AB + 32768;            //    16,384
    float* csz      = csx + 16384;           //    16,384
    float* svec     = csz + 16384;           //    16,384
    unsigned short* MT = (unsigned short*)(svec + 16384);  // 4,194,304 ush

    gram<<<2048, 256, 0, stream>>>(x_feat, z_feat, Gx, Gz, csx, csz);
    proj<<<512, 256, 0, stream>>>(Gx, csx, Wx, bx, kxr, Gz, csz, Wz, bz, kern);
    dy_all<<<64, 256, 0, stream>>>(kern, Wdyn, bdyn, dyb);
    depthpoint<<<dim3(4, 64), 256, 0, stream>>>(dyb, kxr, g_norm, Wp, point, partials);
    lntem<<<64, 256, 0, stream>>>(partials, point, g_norm, b_norm, Wp, bp, murr, AB);
    buildM<<<256, 256, 0, stream>>>(point, murr, AB, Wx, bx, MT, svec);
    final2<<<1024, 256, 0, stream>>>(x_feat, MT, svec, g_ln, b_ln, out);
}

// Round 2
// 297.791 us; speedup vs baseline: 1.0048x; 1.0048x over previous
//
#include <hip/hip_runtime.h>
#include <math.h>

#define EPSV 1e-5f

typedef __attribute__((ext_vector_type(8))) short short8;
typedef __attribute__((ext_vector_type(4))) float f32x4;

// pack two f32 -> two bf16 (RTNE) in one uint
static __device__ __forceinline__ unsigned bfpack2(float lo, float hi) {
    union { float f; unsigned u; } a, b;
    a.f = lo; b.f = hi;
    unsigned ua = a.u + 0x7fffu + ((a.u >> 16) & 1u);
    unsigned ub = b.u + 0x7fffu + ((b.u >> 16) & 1u);
    return (ua >> 16) | (ub & 0xffff0000u);
}

// ---------------------------------------------------------------------------
// K1 gram: G[b] = X_b^T X_b via bf16 MFMA, exploiting symmetry: per batch only
// 3 tiles of 128x128: (0,0),(1,1) diag + (0,1) off-diag (mirror-written).
// Flat grid 384: id<192 x-path (P=1024), else z-path (P=256); b = id&63
// (b -> XCD affinity since 64%8==0), tile = id>>6.
// Staging per 64-p chunk: thread owns 4 cols (cq=(t&31)*4) x 8 p (ph=t>>5);
// float4 global loads (1KB/wave coalescing), pack bf16, LDS [128 c][72 p].
// 4 waves = 2x2 quadrants of the 128x128 output, acc[4][4].
// Column sums (bias outer-product) accumulated on diag tiles.
// ---------------------------------------------------------------------------
__global__ __launch_bounds__(256) void gram(
    const float* __restrict__ Xx, const float* __restrict__ Xz,
    float* __restrict__ Gx, float* __restrict__ Gz,
    float* __restrict__ csx, float* __restrict__ csz)
{
    __shared__ __align__(16) unsigned short AT[128 * 72];
    __shared__ __align__(16) unsigned short BT[128 * 72];
    __shared__ float csr[8 * 128];
    int id = blockIdx.x;
    const float* X; float* G; float* cs; int P;
    if (id < 192) { X = Xx; G = Gx; cs = csx; P = 1024; }
    else { id -= 192; X = Xz; G = Gz; cs = csz; P = 256; }
    const int b = id & 63;
    const int tile = id >> 6;            // 0:(0,0) 1:(1,1) 2:(0,1)
    const int ci = (tile == 1) ? 1 : 0;
    const int cj = (tile == 0) ? 0 : 1;
    const bool diag = (tile < 2);
    const int nk = P >> 6;
    const int t = threadIdx.x;
    const int cq = (t & 31) * 4;         // 4-column base within group
    const int ph = t >> 5;               // p-phase 0..7 (8 p each)
    const float* Xb = X + (long)b * P * 256;

    const int w = t >> 6;
    const int wr = w >> 1, wc = w & 1;   // 64x64 quadrant of output tile
    const int quad = (t >> 4) & 3, lane16 = t & 15;

    f32x4 acc[4][4] = {};
    float csA[4] = {0.f, 0.f, 0.f, 0.f};

    for (int kc = 0; kc < nk; ++kc) {
        const int p0 = kc * 64 + ph * 8;
        float4 va[8], vb[8];
#pragma unroll
        for (int k = 0; k < 8; ++k)
            va[k] = *(const float4*)(Xb + (long)(p0 + k) * 256 + ci * 128 + cq);
        if (!diag) {
#pragma unroll
            for (int k = 0; k < 8; ++k)
                vb[k] = *(const float4*)(Xb + (long)(p0 + k) * 256 + cj * 128 + cq);
        }
        __syncthreads();   // previous chunk's MFMA reads done
#pragma unroll
        for (int j = 0; j < 4; ++j) {
            uint4 pk;
            pk.x = bfpack2(((const float*)&va[0])[j], ((const float*)&va[1])[j]);
            pk.y = bfpack2(((const float*)&va[2])[j], ((const float*)&va[3])[j]);
            pk.z = bfpack2(((const float*)&va[4])[j], ((const float*)&va[5])[j]);
            pk.w = bfpack2(((const float*)&va[6])[j], ((const float*)&va[7])[j]);
            *(uint4*)&AT[(cq + j) * 72 + ph * 8] = pk;
            if (diag) {
                csA[j] += ((const float*)&va[0])[j] + ((const float*)&va[1])[j]
                        + ((const float*)&va[2])[j] + ((const float*)&va[3])[j]
                        + ((const float*)&va[4])[j] + ((const float*)&va[5])[j]
                        + ((const float*)&va[6])[j] + ((const float*)&va[7])[j];
            }
        }
        if (!diag) {
#pragma unroll
            for (int j = 0; j < 4; ++j) {
                uint4 pk;
                pk.x = bfpack2(((const float*)&vb[0])[j], ((const float*)&vb[1])[j]);
                pk.y = bfpack2(((const float*)&vb[2])[j], ((const float*)&vb[3])[j]);
                pk.z = bfpack2(((const float*)&vb[4])[j], ((const float*)&vb[5])[j]);
                pk.w = bfpack2(((const float*)&vb[6])[j], ((const float*)&vb[7])[j]);
                *(uint4*)&BT[(cq + j) * 72 + ph * 8] = pk;
            }
        }
        __syncthreads();
        const unsigned short* Br = diag ? AT : BT;
#pragma unroll
        for (int ks = 0; ks < 2; ++ks) {
            const int ko = ks * 32 + quad * 8;
            short8 bfrag[4];
#pragma unroll
            for (int ni = 0; ni < 4; ++ni)
                bfrag[ni] = *(const short8*)&Br[(wc * 64 + ni * 16 + lane16) * 72 + ko];
#pragma unroll
            for (int mi = 0; mi < 4; ++mi) {
                short8 afrag = *(const short8*)&AT[(wr * 64 + mi * 16 + lane16) * 72 + ko];
#pragma unroll
                for (int ni = 0; ni < 4; ++ni)
                    acc[mi][ni] = __builtin_amdgcn_mfma_f32_16x16x32_bf16(afrag, bfrag[ni], acc[mi][ni], 0, 0, 0);
            }
        }
    }
    // C/D: row = quad*4+r (within mi 16-tile), col = lane16 (within ni 16-tile)
#pragma unroll
    for (int mi = 0; mi < 4; ++mi) {
        const int rbase = ci * 128 + wr * 64 + mi * 16 + quad * 4;
#pragma unroll
        for (int ni = 0; ni < 4; ++ni) {
            const int col = cj * 128 + wc * 64 + ni * 16 + lane16;
#pragma unroll
            for (int r = 0; r < 4; ++r) {
                G[((long)(b * 256 + rbase + r)) * 256 + col] = acc[mi][ni][r];
                if (!diag)  // mirror (G symmetric)
                    G[((long)(b * 256 + col)) * 256 + rbase + r] = acc[mi][ni][r];
            }
        }
    }
    if (diag) {
#pragma unroll
        for (int j = 0; j < 4; ++j) csr[ph * 128 + cq + j] = csA[j];
        __syncthreads();
        if (t < 128) {
            float s = 0.f;
#pragma unroll
            for (int k = 0; k < 8; ++k) s += csr[k * 128 + t];
            cs[b * 256 + ci * 128 + t] = s;
        }
    }
}

// ---------------------------------------------------------------------------
// K2 proj: kxr[b] = Wx^T Gx_b + bx (x) csx_b ; kern[b] = Wz^T Gz_b + bz (x) csz_b.
// G is symmetric => MFMA B-operand reads G rows directly (k = c' contiguous).
// A = W^T staged bf16 once per block ([64 n][264 pad], k = c').
// Flat grid 512: b = id&63, s = id>>6 (s<4: x-path ct=s; else z-path ct=s&3).
// ---------------------------------------------------------------------------
__global__ __launch_bounds__(256) void proj(
    const float* __restrict__ Gx, const float* __restrict__ csx,
    const float* __restrict__ Wx, const float* __restrict__ bx,
    float* __restrict__ kxr,
    const float* __restrict__ Gz, const float* __restrict__ csz,
    const float* __restrict__ Wz, const float* __restrict__ bz,
    float* __restrict__ kern)
{
    __shared__ __align__(16) unsigned short ATW[64 * 264];
    __shared__ __align__(16) unsigned short BTC[64 * 72];
    const int t = threadIdx.x;
    const int id = blockIdx.x;
    const int b = id & 63, s = id >> 6;
    const float *G, *cs, *W, *bias; float* O;
    if (s < 4) { G = Gx; cs = csx; W = Wx; bias = bx; O = kxr; }
    else       { G = Gz; cs = csz; W = Wz; bias = bz; O = kern; }
    const int ct = s & 3;
    const int n = t & 63, ph = t >> 6;
    // stage W^T -> bf16: ATW[n][c'], c' = ph*64 + cc*16 + k
#pragma unroll
    for (int cc = 0; cc < 4; ++cc) {
        float v[16];
#pragma unroll
        for (int k = 0; k < 16; ++k) v[k] = W[(ph * 64 + cc * 16 + k) * 64 + n];
        uint4 p0, p1;
        p0.x = bfpack2(v[0], v[1]);   p0.y = bfpack2(v[2], v[3]);
        p0.z = bfpack2(v[4], v[5]);   p0.w = bfpack2(v[6], v[7]);
        p1.x = bfpack2(v[8], v[9]);   p1.y = bfpack2(v[10], v[11]);
        p1.z = bfpack2(v[12], v[13]); p1.w = bfpack2(v[14], v[15]);
        *(uint4*)&ATW[n * 264 + ph * 64 + cc * 16]     = p0;
        *(uint4*)&ATW[n * 264 + ph * 64 + cc * 16 + 8] = p1;
    }
    const int row = t >> 2, cq = t & 3;
    const int w = t >> 6, quad = (t >> 4) & 3, lane16 = t & 15;
    const float* Grow = G + ((long)(b * 256 + ct * 64 + row)) * 256 + cq * 16;
    f32x4 acc[4] = {{0.f,0.f,0.f,0.f},{0.f,0.f,0.f,0.f},{0.f,0.f,0.f,0.f},{0.f,0.f,0.f,0.f}};
    for (int kc = 0; kc < 4; ++kc) {
        float4 g0 = *(const float4*)(Grow + kc * 64 + 0);
        float4 g1 = *(const float4*)(Grow + kc * 64 + 4);
        float4 g2 = *(const float4*)(Grow + kc * 64 + 8);
        float4 g3 = *(const float4*)(Grow + kc * 64 + 12);
        uint4 pk0, pk1;
        pk0.x = bfpack2(g0.x, g0.y); pk0.y = bfpack2(g0.z, g0.w);
        pk0.z = bfpack2(g1.x, g1.y); pk0.w = bfpack2(g1.z, g1.w);
        pk1.x = bfpack2(g2.x, g2.y); pk1.y = bfpack2(g2.z, g2.w);
        pk1.z = bfpack2(g3.x, g3.y); pk1.w = bfpack2(g3.z, g3.w);
        __syncthreads();
        *(uint4*)&BTC[row * 72 + cq * 16]     = pk0;
        *(uint4*)&BTC[row * 72 + cq * 16 + 8] = pk1;
        __syncthreads();
#pragma unroll
        for (int ks = 0; ks < 2; ++ks) {
            const int ko = ks * 32 + quad * 8;
            short8 bfrag = *(const short8*)&BTC[(w * 16 + lane16) * 72 + ko];
#pragma unroll
            for (int mi = 0; mi < 4; ++mi) {
                short8 afrag = *(const short8*)&ATW[(mi * 16 + lane16) * 264 + kc * 64 + ko];
                acc[mi] = __builtin_amdgcn_mfma_f32_16x16x32_bf16(afrag, bfrag, acc[mi], 0, 0, 0);
            }
        }
    }
    const int col = ct * 64 + w * 16 + lane16;
    const float csv = cs[b * 256 + col];
#pragma unroll
    for (int mi = 0; mi < 4; ++mi) {
        const int nrow = mi * 16 + quad * 4;
#pragma unroll
        for (int r = 0; r < 4; ++r)
            O[((long)(b * 64 + nrow + r)) * 256 + col] = acc[mi][r] + bias[nrow + r] * csv;
    }
}

// ---------------------------------------------------------------------------
// K3: dy = kern @ Wdyn + bdyn. dyb[b][n][68]: 0..63 point, 64..66 depth.
// (unchanged from previous verified kernel)
// ---------------------------------------------------------------------------
__global__ __launch_bounds__(256) void dy_all(
    const float* __restrict__ kern, const float* __restrict__ Wdyn,
    const float* __restrict__ bdyn, float* __restrict__ dyb)
{
    __shared__ float Ac[16 * 64];
    __shared__ float Wc[16 * 64];
    __shared__ float Wd3[48];
    const int b = blockIdx.x, t = threadIdx.x;
    const int tr = t >> 4, tc = t & 15;
    float acc[4][4];
#pragma unroll
    for (int j = 0; j < 4; ++j) {
        float bj = bdyn[3 + tc * 4 + j];
        acc[0][j] = bj; acc[1][j] = bj; acc[2][j] = bj; acc[3][j] = bj;
    }
    const int lr = t >> 2, lc = (t & 3) * 4;
    const int wl = t >> 4, wj = (t & 15) * 4;
    const int nwd = t / 3, jwd = t - nwd * 3;
    float wdacc = 0.f;
    float4 av = *(const float4*)(kern + ((long)(b * 64 + lr)) * 256 + lc);
    float w0 = Wdyn[wl * 67 + 3 + wj + 0];
    float w1 = Wdyn[wl * 67 + 3 + wj + 1];
    float w2 = Wdyn[wl * 67 + 3 + wj + 2];
    float w3 = Wdyn[wl * 67 + 3 + wj + 3];
    float wdr = (t < 48) ? Wdyn[(t / 3) * 67 + (t % 3)] : 0.f;

    for (int c0 = 0; c0 < 256; c0 += 16) {
        Ac[(lc+0)*64 + lr] = av.x; Ac[(lc+1)*64 + lr] = av.y;
        Ac[(lc+2)*64 + lr] = av.z; Ac[(lc+3)*64 + lr] = av.w;
        Wc[wl*64 + wj+0] = w0; Wc[wl*64 + wj+1] = w1;
        Wc[wl*64 + wj+2] = w2; Wc[wl*64 + wj+3] = w3;
        if (t < 48) Wd3[t] = wdr;
        __syncthreads();
        if (c0 + 16 < 256) {
            av = *(const float4*)(kern + ((long)(b * 64 + lr)) * 256 + c0 + 16 + lc);
            w0 = Wdyn[(c0 + 16 + wl) * 67 + 3 + wj + 0];
            w1 = Wdyn[(c0 + 16 + wl) * 67 + 3 + wj + 1];
            w2 = Wdyn[(c0 + 16 + wl) * 67 + 3 + wj + 2];
            w3 = Wdyn[(c0 + 16 + wl) * 67 + 3 + wj + 3];
            if (t < 48) wdr = Wdyn[(c0 + 16 + t / 3) * 67 + (t % 3)];
        }
#pragma unroll
        for (int cl = 0; cl < 16; ++cl) {
            float4 a = *(float4*)&Ac[cl * 64 + tr * 4];
            float4 w = *(float4*)&Wc[cl * 64 + tc * 4];
            acc[0][0]+=a.x*w.x; acc[0][1]+=a.x*w.y; acc[0][2]+=a.x*w.z; acc[0][3]+=a.x*w.w;
            acc[1][0]+=a.y*w.x; acc[1][1]+=a.y*w.y; acc[1][2]+=a.y*w.z; acc[1][3]+=a.y*w.w;
            acc[2][0]+=a.z*w.x; acc[2][1]+=a.z*w.y; acc[2][2]+=a.z*w.z; acc[2][3]+=a.z*w.w;
            acc[3][0]+=a.w*w.x; acc[3][1]+=a.w*w.y; acc[3][2]+=a.w*w.z; acc[3][3]+=a.w*w.w;
        }
        if (t < 192) {
#pragma unroll
            for (int cl = 0; cl < 16; ++cl)
                wdacc += Ac[cl * 64 + nwd] * Wd3[cl * 3 + jwd];
        }
        __syncthreads();
    }
#pragma unroll
    for (int i = 0; i < 4; ++i) {
        float4 o = make_float4(acc[i][0], acc[i][1], acc[i][2], acc[i][3]);
        *(float4*)(dyb + ((long)(b * 64 + tr * 4 + i)) * 68 + tc * 4) = o;
    }
    if (t < 192) dyb[((long)(b * 64 + nwd)) * 68 + 64 + jwd] = wdacc + bdyn[jwd];
}

// ---------------------------------------------------------------------------
// K4: depth conv + point GEMM per (batch, 64-channel tile). grid (4, 64).
// (unchanged from previous verified kernel)
// ---------------------------------------------------------------------------
__global__ __launch_bounds__(256) void depthpoint(
    const float* __restrict__ dyb, const float* __restrict__ v,
    const float* __restrict__ g, const float* __restrict__ Wp,
    float* __restrict__ point, float* __restrict__ partials)
{
    __shared__ float smem[13312];
    float* wpT = smem;           // [m][n] stride 68
    float* wd3 = smem + 4352;    // [m][4]
    float* vt  = smem + 4608;    // [m][lc] stride 68
    float* dep = smem + 8960;    // [m][c_loc] stride 68
    float* rs  = vt;             // alias after depth phase

    const int t = threadIdx.x;
    const int b = blockIdx.y, ct = blockIdx.x, c0 = ct * 64;
    const int tr = t >> 4, tc = t & 15;

#pragma unroll
    for (int i = 0; i < 4; ++i) {
        int idx = t + i * 256; int n = idx >> 4, m0 = (idx & 15) * 4;
        float4 w4 = *(const float4*)(dyb + ((long)(b * 64 + n)) * 68 + m0);
        wpT[(m0+0)*68 + n] = w4.x; wpT[(m0+1)*68 + n] = w4.y;
        wpT[(m0+2)*68 + n] = w4.z; wpT[(m0+3)*68 + n] = w4.w;
    }
    if (t < 64) {
        long o = ((long)(b * 64 + t)) * 68 + 64;
        wd3[t*4+0] = dyb[o+0]; wd3[t*4+1] = dyb[o+1]; wd3[t*4+2] = dyb[o+2];
    }
    {
        int m = t >> 2, lc0 = (t & 3) * 17;
#pragma unroll
        for (int k = 0; k < 17; ++k) {
            int lc = lc0 + k;
            if (lc < 66) {
                int c = c0 - 1 + lc;
                vt[m * 68 + lc] = (c >= 0 && c < 256) ? v[((long)(b * 64 + m)) * 256 + c] : 0.f;
            }
        }
    }
    __syncthreads();
#pragma unroll
    for (int im = 0; im < 4; ++im) {
        int m = tr * 4 + im;
        float w0 = wd3[m*4+0], w1 = wd3[m*4+1], w2 = wd3[m*4+2];
#pragma unroll
        for (int jc = 0; jc < 4; ++jc) {
            int cl = tc * 4 + jc;
            float d = w0 * vt[m*68 + cl] + w1 * vt[m*68 + cl + 1] + w2 * vt[m*68 + cl + 2];
            dep[m*68 + cl] = fmaxf(d, 0.f);
        }
    }
    __syncthreads();
    float acc[4][4] = {};
#pragma unroll 16
    for (int m = 0; m < 64; ++m) {
        float4 a4 = *(float4*)&wpT[m * 68 + tr * 4];
        float4 d4 = *(float4*)&dep[m * 68 + tc * 4];
        acc[0][0]+=a4.x*d4.x; acc[0][1]+=a4.x*d4.y; acc[0][2]+=a4.x*d4.z; acc[0][3]+=a4.x*d4.w;
        acc[1][0]+=a4.y*d4.x; acc[1][1]+=a4.y*d4.y; acc[1][2]+=a4.y*d4.z; acc[1][3]+=a4.y*d4.w;
        acc[2][0]+=a4.z*d4.x; acc[2][1]+=a4.z*d4.y; acc[2][2]+=a4.z*d4.z; acc[2][3]+=a4.z*d4.w;
        acc[3][0]+=a4.w*d4.x; acc[3][1]+=a4.w*d4.y; acc[3][2]+=a4.w*d4.z; acc[3][3]+=a4.w*d4.w;
    }
    int cg = c0 + tc * 4;
    float4 g4  = *(const float4*)(g + cg);
    float4 wp4 = *(const float4*)(Wp + cg);
    float gw0 = g4.x*wp4.x, gw1 = g4.y*wp4.y, gw2 = g4.z*wp4.z, gw3 = g4.w*wp4.w;
#pragma unroll
    for (int i = 0; i < 4; ++i) {
        float4 o = make_float4(acc[i][0], acc[i][1], acc[i][2], acc[i][3]);
        *(float4*)(point + ((long)(b * 64 + tr * 4 + i)) * 256 + cg) = o;
        float s  = o.x + o.y + o.z + o.w;
        float s2 = o.x*o.x + o.y*o.y + o.z*o.z + o.w*o.w;
        float dg = o.x*gw0 + o.y*gw1 + o.z*gw2 + o.w*gw3;
        rs[0*1088 + (tr*4+i)*17 + tc] = s;
        rs[1*1088 + (tr*4+i)*17 + tc] = s2;
        rs[2*1088 + (tr*4+i)*17 + tc] = dg;
    }
    __syncthreads();
    if (t < 64) {
        float s = 0.f, s2 = 0.f, dg = 0.f;
#pragma unroll
        for (int j = 0; j < 16; ++j) {
            s  += rs[t*17 + j];
            s2 += rs[1088 + t*17 + j];
            dg += rs[2176 + t*17 + j];
        }
        long base = ((long)(b * 4 + ct)) * 192;
        partials[base + t]        = s;
        partials[base + 64 + t]   = s2;
        partials[base + 128 + t]  = dg;
    }
}

// ---------------------------------------------------------------------------
// K5: LN stats + proto (closed form) + tem. Emits murr[b][n]=(rr,-mu*rr),
// AB[b] = (g_norm*tem, b_norm*tem). (unchanged from previous verified kernel)
// ---------------------------------------------------------------------------
__global__ __launch_bounds__(256) void lntem(
    const float* __restrict__ partials, const float* __restrict__ point,
    const float* __restrict__ g, const float* __restrict__ bta,
    const float* __restrict__ Wp, const float* __restrict__ bp,
    float* __restrict__ murr, float* __restrict__ AB)
{
    __shared__ float sA[256], sB[256];
    __shared__ float wnv[64];
    __shared__ float tot[4];
    const int b = blockIdx.x, t = threadIdx.x;
    const int c = t;
    float gc = g[c], bc = bta[c], wpc = Wp[c];
    sA[t] = gc * wpc; sB[t] = bc * wpc;
    __syncthreads();
    for (int off = 128; off >= 1; off >>= 1) {
        if (t < off) { sA[t] += sA[t+off]; sB[t] += sB[t+off]; }
        __syncthreads();
    }
    if (t == 0) { tot[0] = sA[0]; tot[1] = sB[0] + bp[0]; }
    __syncthreads();
    float Sgw = tot[0], Sbw = tot[1];

    float protoe = 0.f, mu = 0.f, rr = 0.f;
    if (t < 64) {
        float S1 = 0.f, S2 = 0.f, Sdg = 0.f;
#pragma unroll
        for (int ct = 0; ct < 4; ++ct) {
            long o = ((long)(b * 4 + ct)) * 192;
            S1 += partials[o + t]; S2 += partials[o + 64 + t]; Sdg += partials[o + 128 + t];
        }
        mu = S1 * (1.f / 256.f);
        float var = S2 * (1.f / 256.f) - mu * mu;
        rr = rsqrtf(var + EPSV);
        protoe = rr * (Sdg - mu * Sgw) + Sbw;
        wnv[t] = protoe * rr;
        murr[b * 128 + 2*t]     = rr;
        murr[b * 128 + 2*t + 1] = -mu * rr;
    }
    __syncthreads();
    sA[t] = (t < 64) ? protoe * rr * mu : 0.f;
    sB[t] = (t < 64) ? protoe : 0.f;
    __syncthreads();
    for (int off = 128; off >= 1; off >>= 1) {
        if (t < off) { sA[t] += sA[t+off]; sB[t] += sB[t+off]; }
        __syncthreads();
    }
    if (t == 0) { tot[2] = sA[0]; tot[3] = sB[0]; }
    __syncthreads();
    float Bv = tot[2], Sv = tot[3];

    const float* pcol = point + (long)b * 64 * 256 + c;
    float a0 = 0.f, a1 = 0.f, a2 = 0.f, a3 = 0.f;
#pragma unroll
    for (int n = 0; n < 64; n += 4) {
        a0 += wnv[n+0] * pcol[(n+0) * 256];
        a1 += wnv[n+1] * pcol[(n+1) * 256];
        a2 += wnv[n+2] * pcol[(n+2) * 256];
        a3 += wnv[n+3] * pcol[(n+3) * 256];
    }
    float accA = a0 + a1 + a2 + a3;
    float x = gc * (accA - Bv) + bc * Sv;
    float temv = 1.f / (1.f + expf(-x));
    AB[b * 512 + c]       = gc * temv;
    AB[b * 512 + 256 + c] = bc * temv;
}

// ---------------------------------------------------------------------------
// K6 buildM: kxs[n][c] = (point*rr - mu*rr)*g*tem + b*tem.
// MT[b][cout][cin] = sum_n kxs[n][cout] * Wx[cin][n] (bf16, cin contiguous).
// svec[b][c] = sum_n bx[n]*kxs[n][c]. Flat grid 256: b=id&63, mt=id>>6.
// (unchanged from previous verified kernel)
// ---------------------------------------------------------------------------
__global__ __launch_bounds__(256) void buildM(
    const float* __restrict__ point, const float* __restrict__ murr,
    const float* __restrict__ AB, const float* __restrict__ Wx,
    const float* __restrict__ bx,
    unsigned short* __restrict__ MT, float* __restrict__ svec)
{
    __shared__ float ks_s[64 * 68];   // kxs [n][cout-local]
    __shared__ float wt_s[64 * 68];   // WxT chunk [n][cin-local]
    const int t = threadIdx.x;
    const int id = blockIdx.x;
    const int b = id & 63, mt = id >> 6;
    {
        const int n = t >> 2, q = t & 3;
        const float rn = murr[b * 128 + 2 * n], qn = murr[b * 128 + 2 * n + 1];
        const float* prow = point + ((long)(b * 64 + n)) * 256 + mt * 64 + q * 16;
        const float* Arow = AB + b * 512 + mt * 64 + q * 16;
#pragma unroll
        for (int j = 0; j < 4; ++j) {
            float4 p4 = *(const float4*)(prow + j * 4);
            float4 A4 = *(const float4*)(Arow + j * 4);
            float4 B4 = *(const float4*)(Arow + 256 + j * 4);
            float4 kv;
            kv.x = (p4.x * rn + qn) * A4.x + B4.x;
            kv.y = (p4.y * rn + qn) * A4.y + B4.y;
            kv.z = (p4.z * rn + qn) * A4.z + B4.z;
            kv.w = (p4.w * rn + qn) * A4.w + B4.w;
            *(float4*)&ks_s[n * 68 + q * 16 + j * 4] = kv;
        }
    }
    __syncthreads();
    if (t < 64) {
        float sv = 0.f;
#pragma unroll
        for (int n2 = 0; n2 < 64; ++n2) sv += bx[n2] * ks_s[n2 * 68 + t];
        svec[b * 256 + mt * 64 + t] = sv;
    }
    const int tr = t >> 4, tc = t & 15;
    const int nw = t & 63, ph = t >> 6;
    for (int cc = 0; cc < 4; ++cc) {
        float wv[16];
#pragma unroll
        for (int k = 0; k < 16; ++k) wv[k] = Wx[(cc * 64 + ph * 16 + k) * 64 + nw];
        __syncthreads();   // previous chunk's compute reads done
#pragma unroll
        for (int k = 0; k < 16; ++k) wt_s[nw * 68 + ph * 16 + k] = wv[k];
        __syncthreads();
        float a2[4][4] = {};
#pragma unroll 16
        for (int n2 = 0; n2 < 64; ++n2) {
            float4 a4 = *(float4*)&ks_s[n2 * 68 + tr * 4];   // cout
            float4 w4 = *(float4*)&wt_s[n2 * 68 + tc * 4];   // cin
            a2[0][0]+=a4.x*w4.x; a2[0][1]+=a4.x*w4.y; a2[0][2]+=a4.x*w4.z; a2[0][3]+=a4.x*w4.w;
            a2[1][0]+=a4.y*w4.x; a2[1][1]+=a4.y*w4.y; a2[1][2]+=a4.y*w4.z; a2[1][3]+=a4.y*w4.w;
            a2[2][0]+=a4.z*w4.x; a2[2][1]+=a4.z*w4.y; a2[2][2]+=a4.z*w4.z; a2[2][3]+=a4.z*w4.w;
            a2[3][0]+=a4.w*w4.x; a2[3][1]+=a4.w*w4.y; a2[3][2]+=a4.w*w4.z; a2[3][3]+=a4.w*w4.w;
        }
#pragma unroll
        for (int i = 0; i < 4; ++i) {
            uint2 pk;
            pk.x = bfpack2(a2[i][0], a2[i][1]);
            pk.y = bfpack2(a2[i][2], a2[i][3]);
            *(uint2*)&MT[((long)(b * 256 + mt * 64 + tr * 4 + i)) * 256 + cc * 64 + tc * 4] = pk;
        }
    }
}

// ---------------------------------------------------------------------------
// K7 final2: x_corr = X_b @ M + svec via bf16 MFMA, then row LN + relu +
// residual. 32-row tiles: flat grid 2048, b = id&63 (XCD affinity for MT_b),
// pt = id>>6 (32-row tile). acc[2][4]; LDS ~18KB; shorter phases + 2x blocks
// for latency overlap vs the 64-row version.
// ---------------------------------------------------------------------------
__global__ __launch_bounds__(256) void final2(
    const float* __restrict__ xf, const unsigned short* __restrict__ MT,
    const float* __restrict__ svec, const float* __restrict__ g,
    const float* __restrict__ bt, float* __restrict__ out)
{
    __shared__ __align__(16) float SlArr[32 * 132];   // 16896B: XT (bf16) / Sl (f32) union
    __shared__ float red1[128], red2[128];
    __shared__ float muS[32], rrS[32];
    unsigned short* XT = (unsigned short*)SlArr;      // [32 p][264 pad] bf16
    float* Sl = SlArr;                                // [32 p][132] f32
    const int t = threadIdx.x;
    const int id = blockIdx.x;
    const int b = id & 63, pt = id >> 6;              // pt 0..31
    const int w = t >> 6, quad = (t >> 4) & 3, lane16 = t & 15;
    const float* Xb = xf + ((long)(b * 1024 + pt * 32)) * 256;
    {
        const int p = t >> 3, q = t & 7;
#pragma unroll
        for (int i = 0; i < 8; ++i) {
            const int c = q * 32 + i * 4;
            float4 v = *(const float4*)(Xb + (long)p * 256 + c);
            uint2 pk;
            pk.x = bfpack2(v.x, v.y);
            pk.y = bfpack2(v.z, v.w);
            *(uint2*)&XT[p * 264 + c] = pk;
        }
    }
    __syncthreads();
    f32x4 acc[2][4] = {};   // [mi (rows)][ni (cols)]
    const unsigned short* Mb = MT + (long)b * 65536;
    for (int ks = 0; ks < 8; ++ks) {
        const int ko = ks * 32 + quad * 8;
        short8 bf4[4], af2[2];
#pragma unroll
        for (int ni = 0; ni < 4; ++ni)
            bf4[ni] = *(const short8*)(Mb + (long)(w * 64 + ni * 16 + lane16) * 256 + ko);
#pragma unroll
        for (int mi = 0; mi < 2; ++mi)
            af2[mi] = *(const short8*)&XT[(mi * 16 + lane16) * 264 + ko];
#pragma unroll
        for (int mi = 0; mi < 2; ++mi)
#pragma unroll
            for (int ni = 0; ni < 4; ++ni)
                acc[mi][ni] = __builtin_amdgcn_mfma_f32_16x16x32_bf16(af2[mi], bf4[ni], acc[mi][ni], 0, 0, 0);
    }
    // add svec, per-row (256-col) sums for LN
    float sv4[4];
#pragma unroll
    for (int ni = 0; ni < 4; ++ni) sv4[ni] = svec[b * 256 + w * 64 + ni * 16 + lane16];
#pragma unroll
    for (int mi = 0; mi < 2; ++mi)
#pragma unroll
        for (int r = 0; r < 4; ++r) {
            float s1 = 0.f, s2 = 0.f;
#pragma unroll
            for (int ni = 0; ni < 4; ++ni) {
                float v2 = acc[mi][ni][r] + sv4[ni];
                acc[mi][ni][r] = v2;
                s1 += v2; s2 += v2 * v2;
            }
            // butterfly over the 16 lanes of this quad
#pragma unroll
            for (int m = 1; m <= 8; m <<= 1) {
                s1 += __shfl_xor(s1, m);
                s2 += __shfl_xor(s2, m);
            }
            if (lane16 == 0) {
                red1[(mi * 16 + quad * 4 + r) * 4 + w] = s1;
                red2[(mi * 16 + quad * 4 + r) * 4 + w] = s2;
            }
        }
    __syncthreads();
    if (t < 32) {
        float sa = red1[t*4] + red1[t*4+1] + red1[t*4+2] + red1[t*4+3];
        float sb = red2[t*4] + red2[t*4+1] + red2[t*4+2] + red2[t*4+3];
        float m = sa * (1.f / 256.f);
        muS[t] = m;
        rrS[t] = rsqrtf(sb * (1.f / 256.f) - m * m + EPSV);
    }
    // scatter (MFMA layout) -> LDS -> vectorized LN+relu+residual store, 2 halves
#pragma unroll
    for (int h = 0; h < 2; ++h) {
        __syncthreads();
        if ((w >> 1) == h) {
            const int chalf = (w & 1) * 64;
#pragma unroll
            for (int mi = 0; mi < 2; ++mi)
#pragma unroll
                for (int ni = 0; ni < 4; ++ni)
#pragma unroll
                    for (int r = 0; r < 4; ++r)
                        Sl[(mi * 16 + quad * 4 + r) * 132 + chalf + ni * 16 + lane16] = acc[mi][ni][r];
        }
        __syncthreads();
        {
            const int p = t >> 3, q = t & 7;
            const float m = muS[p], rr = rrS[p];
            const long grow = ((long)(b * 1024 + pt * 32 + p)) * 256;
#pragma unroll
            for (int j = 0; j < 4; ++j) {
                const int cl = q * 16 + j * 4;
                const int c = h * 128 + cl;
                float4 a  = *(float4*)&Sl[p * 132 + cl];
                float4 g4 = *(const float4*)(g + c);
                float4 b4 = *(const float4*)(bt + c);
                float4 xv = *(const float4*)(xf + grow + c);
                float4 o;
                o.x = xv.x + fmaxf((a.x - m) * rr * g4.x + b4.x, 0.f);
                o.y = xv.y + fmaxf((a.y - m) * rr * g4.y + b4.y, 0.f);
                o.z = xv.z + fmaxf((a.z - m) * rr * g4.z + b4.z, 0.f);
                o.w = xv.w + fmaxf((a.w - m) * rr * g4.w + b4.w, 0.f);
                *(float4*)(out + grow + c) = o;
            }
        }
    }
}

extern "C" void kernel_launch(void* const* d_in, const int* in_sizes, int n_in,
                              void* d_out, int out_size, void* d_ws, size_t ws_size,
                              hipStream_t stream)
{
    (void)in_sizes; (void)n_in; (void)out_size; (void)ws_size;
    const float* x_feat = (const float*)d_in[0];
    const float* z_feat = (const float*)d_in[1];
    const float* Wz     = (const float*)d_in[2];
    const float* bz     = (const float*)d_in[3];
    const float* Wx     = (const float*)d_in[4];
    const float* bx     = (const float*)d_in[5];
    const float* Wdyn   = (const float*)d_in[6];
    const float* bdyn   = (const float*)d_in[7];
    const float* g_norm = (const float*)d_in[8];
    const float* b_norm = (const float*)d_in[9];
    const float* Wp     = (const float*)d_in[10];
    const float* bp     = (const float*)d_in[11];
    const float* g_ln   = (const float*)d_in[12];
    const float* b_ln   = (const float*)d_in[13];
    float* out = (float*)d_out;

    float* ws       = (float*)d_ws;
    float* Gx       = ws;                    // 4,194,304 f32
    float* Gz       = Gx + 4194304;          // 4,194,304
    float* kern     = Gz + 4194304;          // 1,048,576
    float* kxr      = kern + 1048576;        // 1,048,576
    float* point    = kxr + 1048576;         // 1,048,576
    float* dyb      = point + 1048576;       //   278,528
    float* partials = dyb + 278528;          //    49,152
    float* murr     = partials + 49152;      //     8,192
    float* AB       = murr + 8192;           //    32,768
    float* csx      = AB + 32768;            //    16,384
    float* csz      = csx + 16384;           //    16,384
    float* svec     = csz + 16384;           //    16,384
    unsigned short* MT = (unsigned short*)(svec + 16384);  // 4,194,304 ush

    gram<<<384, 256, 0, stream>>>(x_feat, z_feat, Gx, Gz, csx, csz);
    proj<<<512, 256, 0, stream>>>(Gx, csx, Wx, bx, kxr, Gz, csz, Wz, bz, kern);
    dy_all<<<64, 256, 0, stream>>>(kern, Wdyn, bdyn, dyb);
    depthpoint<<<dim3(4, 64), 256, 0, stream>>>(dyb, kxr, g_norm, Wp, point, partials);
    lntem<<<64, 256, 0, stream>>>(partials, point, g_norm, b_norm, Wp, bp, murr, AB);
    buildM<<<256, 256, 0, stream>>>(point, murr, AB, Wx, bx, MT, svec);
    final2<<<2048, 256, 0, stream>>>(x_feat, MT, svec, g_ln, b_ln, out);
}